// Round 5
// baseline (337.213 us; speedup 1.0000x reference)
//
#include <hip/hip_runtime.h>

#define H      128
#define OBSROW 141
#define GPB    16     // graphs per block (MFMA M dimension)
#define NT     1024   // 16 waves: (half = wave>>3) x (o-tile jt = wave&7)

typedef __bf16 bf16x8 __attribute__((ext_vector_type(8)));
typedef float  f32x4  __attribute__((ext_vector_type(4)));

__device__ __forceinline__ unsigned short f2bf(float f) {
    unsigned int u = __builtin_bit_cast(unsigned int, f);
    u += 0x7fffu + ((u >> 16) & 1u);          // round-to-nearest-even
    return (unsigned short)(u >> 16);
}
__device__ __forceinline__ float eluf(float v) {
    return v > 0.0f ? v : (__expf(v) - 1.0f);
}

union BFU { unsigned short s[8]; bf16x8 v; };

// ws (bf16 elems): [0)Wrel 3*16384 | [49152)Wroot 3*16384 | [98304)We_b pad[128][64] | [106496)We_j pad[128][32]
#define WS_ROOT 49152
#define WS_EB   98304
#define WS_EJ   106496
#define WS_TOT  110592

__global__ void convert_weights(const float* __restrict__ Wr, const float* __restrict__ Wo,
                                const float* __restrict__ Web, const float* __restrict__ Wej,
                                unsigned short* __restrict__ ws) {
    const int i = blockIdx.x * 256 + threadIdx.x;
    if (i < WS_ROOT) {
        ws[i] = f2bf(Wr[i]);
    } else if (i < WS_EB) {
        ws[i] = f2bf(Wo[i - WS_ROOT]);
    } else if (i < WS_EJ) {
        const int j = i - WS_EB, o = j >> 6, f = j & 63;
        ws[i] = f2bf(f < 33 ? Web[o*33 + f] : 0.0f);
    } else if (i < WS_TOT) {
        const int j = i - WS_EJ, o = j >> 5, f = j & 31;
        ws[i] = f2bf(f < 9 ? Wej[o*9 + f] : 0.0f);
    }
}

// X layout: [node 13][hc=h/8 16][graph 16][hi 8]  (bf16) -> A-frag = 16B contiguous
#define XIDX(n,hc,g,hi) (((((n)*16 + (hc))*16 + (g))*8) + (hi))

__launch_bounds__(NT, 4)   // 4 waves/EU -> 128-reg cap; streaming acc keeps demand ~90
__global__ void gnn_fused(const float* __restrict__ obs,
                          const float* __restrict__ be_b, const float* __restrict__ be_j,
                          const float* __restrict__ b_rel,
                          const float* __restrict__ W_dec, const float* __restrict__ b_dec,
                          const unsigned short* __restrict__ wsb,
                          float* __restrict__ out, int B)
{
    __shared__ __align__(16) unsigned short Xs[13*2048];   // 53248 B
    __shared__ __align__(16) unsigned short Ag[13*2048];   // 53248 B (also obs staging)

    const int tid  = threadIdx.x;
    const int wave = tid >> 6;     // 0..15
    const int half = wave >> 3;    // node-subset
    const int jt   = wave & 7;     // o-tile
    const int lane = tid & 63;
    const int q    = lane >> 4;    // quad 0..3
    const int c    = lane & 15;    // col-in-tile / graph-in-chunk
    const int g0   = blockIdx.x * GPB;
    const int o    = jt*16 + c;

    // per-thread LDS bases for A-frag reads: frag(n,k) at base + n*2048 + k*512 shorts
    const unsigned short* xrd = Xs + q*128 + c*8;
    const unsigned short* ard = Ag + q*128 + c*8;

    // in-edge adjacency of the fixed 24-edge tree (both directions folded in)
    static constexpr int INDEG[13]    = {4,2,2,1,2,2,1,2,2,1,2,2,1};
    static constexpr int INSRC[13][4] = {
        {1,4,7,10},{0,2,0,0},{1,3,0,0},{2,0,0,0},{0,5,0,0},{4,6,0,0},{5,0,0,0},
        {0,8,0,0},{7,9,0,0},{8,0,0,0},{0,11,0,0},{10,12,0,0},{11,0,0,0}};

    // ---------------- stage obs features into Ag ----------------
    // joints at Ag[jj*512 + fc*128 + g*8 + hi] (jj 0..11, f = fc*8+hi, f<9 valid)
    for (int s = tid; s < 6144; s += NT) {
        const int jj = s >> 9, rem = s & 511;
        const int fc = rem >> 7, g = (rem >> 3) & 15, hi = rem & 7;
        const int f = fc*8 + hi;
        float v = 0.0f;
        if (f < 9 && (g0 + g) < B)
            v = obs[(g0+g)*OBSROW + (f/3)*47 + 9 + (f%3)*12 + jj];
        Ag[s] = f2bf(v);
    }
    // base at Ag[6144 + fc*128 + g*8 + hi] (f = fc*8+hi, f<33 valid, K padded to 64)
    if (tid < 1024) {
        const int s = tid;
        const int fc = s >> 7, rem = s & 127, g = rem >> 3, hi = rem & 7;
        const int f = fc*8 + hi;
        float v = 0.0f;
        if (f < 33 && (g0 + g) < B) {
            const int tt = f / 11, i2 = f % 11;   // BASE_IDX[i] = i<9 ? i : 36+i
            v = obs[(g0+g)*OBSROW + tt*47 + (i2 < 9 ? i2 : 36 + i2)];
        }
        Ag[6144 + s] = f2bf(v);
    }
    __syncthreads();

    // ---------------- encoders ----------------
    if (half == 0) {   // node 0 (base), K=64 -> 2 MFMAs
        const bf16x8 u0 = *(const bf16x8*)(wsb + WS_EB + o*64 + q*8);
        const bf16x8 u1 = *(const bf16x8*)(wsb + WS_EB + o*64 + 32 + q*8);
        const bf16x8 a0 = *(const bf16x8*)&Ag[6144 + q*128 + c*8];
        const bf16x8 a1 = *(const bf16x8*)&Ag[6144 + 512 + q*128 + c*8];
        f32x4 acc = {0.f,0.f,0.f,0.f};
        acc = __builtin_amdgcn_mfma_f32_16x16x32_bf16(a0, u0, acc, 0,0,0);
        acc = __builtin_amdgcn_mfma_f32_16x16x32_bf16(a1, u1, acc, 0,0,0);
        const float bias = be_b[o];
        #pragma unroll
        for (int r = 0; r < 4; r++)
            Xs[XIDX(0, jt*2 + (c>>3), q*4 + r, c & 7)] = f2bf(eluf(acc[r] + bias));
    }
    {   // joints: each wave does 6 of them for its o-tile, K=32 -> 1 MFMA each
        const bf16x8 uj = *(const bf16x8*)(wsb + WS_EJ + o*32 + q*8);
        const float bias = be_j[o];
        #pragma unroll
        for (int t2 = 0; t2 < 6; t2++) {
            const int jj = half*6 + t2;
            const bf16x8 a = *(const bf16x8*)&Ag[jj*512 + q*128 + c*8];
            f32x4 acc = {0.f,0.f,0.f,0.f};
            acc = __builtin_amdgcn_mfma_f32_16x16x32_bf16(a, uj, acc, 0,0,0);
            #pragma unroll
            for (int r = 0; r < 4; r++)
                Xs[XIDX(1+jj, jt*2 + (c>>3), q*4 + r, c & 7)] = f2bf(eluf(acc[r] + bias));
        }
    }
    __syncthreads();

    // ---------------- 3 GraphConv layers ----------------
    #pragma unroll 1
    for (int l = 0; l < 3; l++) {
        // preload this wave's B-frags (bf16, direct dwordx4) — overlaps agg compute
        bf16x8 brel[4], broot[4];
        #pragma unroll
        for (int k = 0; k < 4; k++) {
            brel[k]  = *(const bf16x8*)(wsb + l*16384 + o*128 + k*32 + q*8);
            broot[k] = *(const bf16x8*)(wsb + WS_ROOT + l*16384 + o*128 + k*32 + q*8);
        }
        // agg[n] = sum of x[src] (element-wise, vectorized by 8): 3328 vec-slots
        for (int i = tid; i < 3328; i += NT) {
            const int n = i >> 8, off = (i & 255) << 3;
            const bf16x8 v0 = *(const bf16x8*)&Xs[INSRC[n][0]*2048 + off];
            float s[8];
            #pragma unroll
            for (int j = 0; j < 8; j++) s[j] = (float)v0[j];
            #pragma unroll
            for (int e = 1; e < 4; e++)
                if (e < INDEG[n]) {
                    const bf16x8 ve = *(const bf16x8*)&Xs[INSRC[n][e]*2048 + off];
                    #pragma unroll
                    for (int j = 0; j < 8; j++) s[j] += (float)ve[j];
                }
            BFU r;
            #pragma unroll
            for (int j = 0; j < 8; j++) r.s[j] = f2bf(s[j]);
            *(bf16x8*)&Ag[n*2048 + off] = r.v;
        }
        __syncthreads();
        // per node: acc = W_rel·agg[n] + W_root·x[n]  (single 4-reg accumulator)
        const float bias = b_rel[l*H + o];
        const int n0  = half*7;        // half0: nodes 0..6, half1: 7..12
        const int cnt = 7 - half;
        unsigned int stash[7][2];
        #pragma unroll
        for (int idx = 0; idx < 7; idx++) {
            if (idx < cnt) {
                const int n = n0 + idx;
                f32x4 acc = {0.f,0.f,0.f,0.f};
                #pragma unroll
                for (int k = 0; k < 4; k++)
                    acc = __builtin_amdgcn_mfma_f32_16x16x32_bf16(
                        *(const bf16x8*)(ard + n*2048 + k*512), brel[k], acc, 0,0,0);
                #pragma unroll
                for (int k = 0; k < 4; k++)
                    acc = __builtin_amdgcn_mfma_f32_16x16x32_bf16(
                        *(const bf16x8*)(xrd + n*2048 + k*512), broot[k], acc, 0,0,0);
                const float v0 = eluf(acc[0] + bias);
                const float v1 = eluf(acc[1] + bias);
                const float v2 = eluf(acc[2] + bias);
                const float v3 = eluf(acc[3] + bias);
                stash[idx][0] = (unsigned)f2bf(v0) | ((unsigned)f2bf(v1) << 16);
                stash[idx][1] = (unsigned)f2bf(v2) | ((unsigned)f2bf(v3) << 16);
            }
        }
        __syncthreads();   // all waves done reading Xs/Ag
        {
            const int hc = jt*2 + (c >> 3);
            const int hi = c & 7;
            #pragma unroll
            for (int idx = 0; idx < 7; idx++) {
                if (idx < cnt) {
                    const int n = n0 + idx;
                    Xs[XIDX(n, hc, q*4+0, hi)] = (unsigned short)(stash[idx][0]);
                    Xs[XIDX(n, hc, q*4+1, hi)] = (unsigned short)(stash[idx][0] >> 16);
                    Xs[XIDX(n, hc, q*4+2, hi)] = (unsigned short)(stash[idx][1]);
                    Xs[XIDX(n, hc, q*4+3, hi)] = (unsigned short)(stash[idx][1] >> 16);
                }
            }
        }
        __syncthreads();   // new X visible
    }

    // ---------------- decoder: out[g][j] = x[j+1]·W_dec + b_dec ----------------
    if (wave < 12) {
        // decoder base: hc = q*4 + hq  ->  h = q*32 + hq*8 + hi (matches wd indexing)
        const unsigned short* xdec = Xs + q*512 + c*8;
        float wd[32];
        #pragma unroll
        for (int i4 = 0; i4 < 8; i4++) {
            const float4 wv = *(const float4*)&W_dec[q*32 + i4*4];
            wd[i4*4+0] = wv.x; wd[i4*4+1] = wv.y; wd[i4*4+2] = wv.z; wd[i4*4+3] = wv.w;
        }
        const float bd = b_dec[0];
        const int j = wave;                 // joint 0..11
        float s = 0.0f;
        #pragma unroll
        for (int hq = 0; hq < 4; hq++) {    // lane covers h = q*32 + hq*8 + hi
            const bf16x8 xv = *(const bf16x8*)(xdec + (j+1)*2048 + hq*128);
            #pragma unroll
            for (int hi = 0; hi < 8; hi++)
                s += (float)xv[hi] * wd[hq*8 + hi];
        }
        s += __shfl_xor(s, 16);
        s += __shfl_xor(s, 32);
        if (q == 0 && (g0 + c) < B)
            out[(g0 + c)*12 + j] = s + bd;
    }
}

extern "C" void kernel_launch(void* const* d_in, const int* in_sizes, int n_in,
                              void* d_out, int out_size, void* d_ws, size_t ws_size,
                              hipStream_t stream) {
    const float* obs   = (const float*)d_in[0];
    const float* We_b  = (const float*)d_in[1];
    const float* be_b  = (const float*)d_in[2];
    const float* We_j  = (const float*)d_in[3];
    const float* be_j  = (const float*)d_in[4];
    const float* W_rel = (const float*)d_in[5];
    const float* W_root= (const float*)d_in[6];
    const float* b_rel = (const float*)d_in[7];
    const float* W_dec = (const float*)d_in[8];
    const float* b_dec = (const float*)d_in[9];
    // d_in[10]/d_in[11] (src/dst) are the fixed tree edges; adjacency is baked in.
    float* out = (float*)d_out;
    unsigned short* wsb = (unsigned short*)d_ws;   // 221 KB of bf16 weights

    const int B = in_sizes[0] / OBSROW;
    convert_weights<<<(WS_TOT + 255) / 256, 256, 0, stream>>>(W_rel, W_root, We_b, We_j, wsb);
    const int blocks = (B + GPB - 1) / GPB;
    gnn_fused<<<blocks, NT, 0, stream>>>(obs, be_b, be_j, b_rel, W_dec, b_dec,
                                         wsb, out, B);
}

// Round 6
// 292.879 us; speedup vs baseline: 1.1514x; 1.1514x over previous
//
#include <hip/hip_runtime.h>

#define H      128
#define OBSROW 141
#define GPB    16     // graphs per block (MFMA M dimension)
#define NT     1024   // 16 waves = 8 o-tiles x 2 node-halves

typedef __bf16 bf16x8 __attribute__((ext_vector_type(8)));
typedef __bf16 bf16x4 __attribute__((ext_vector_type(4)));
typedef float  f32x4  __attribute__((ext_vector_type(4)));

__device__ __forceinline__ unsigned short f2bf(float f) {
    unsigned int u = __builtin_bit_cast(unsigned int, f);
    u += 0x7fffu + ((u >> 16) & 1u);          // round-to-nearest-even
    return (unsigned short)(u >> 16);
}
__device__ __forceinline__ float eluf(float v) {
    return v > 0.0f ? v : (__expf(v) - 1.0f);
}

// ws (bf16 elems): [0)Wrel 3*16384 | [49152)Wroot 3*16384 | [98304)We_b pad[128][64] | [106496)We_j pad[128][32]
#define WS_ROOT 49152
#define WS_EB   98304
#define WS_EJ   106496
#define WS_TOT  110592

__global__ void convert_weights(const float* __restrict__ Wr, const float* __restrict__ Wo,
                                const float* __restrict__ Web, const float* __restrict__ Wej,
                                unsigned short* __restrict__ ws) {
    const int i = blockIdx.x * 256 + threadIdx.x;
    if (i < WS_ROOT) {
        ws[i] = f2bf(Wr[i]);
    } else if (i < WS_EB) {
        ws[i] = f2bf(Wo[i - WS_ROOT]);
    } else if (i < WS_EJ) {
        const int j = i - WS_EB, o = j >> 6, f = j & 63;
        ws[i] = f2bf(f < 33 ? Web[o*33 + f] : 0.0f);
    } else if (i < WS_TOT) {
        const int j = i - WS_EJ, o = j >> 5, f = j & 31;
        ws[i] = f2bf(f < 9 ? Wej[o*9 + f] : 0.0f);
    }
}

// X layout: [node 13][hc=h/8 16][graph 16][hi 8]  (bf16) -> A-frag = 16B contiguous
#define XIDX(n,hc,g,hi) (((((n)*16 + (hc))*16 + (g))*8) + (hi))
// Yrel layout: [node 13][jt 8][lane 64][4 bf16]  (C-layout per lane, 8B units)
#define YIDX(n,jj,ln)  (((((n)*8 + (jj))*64) + (ln))*4)

__launch_bounds__(NT, 4)   // 4 waves/EU -> 128-reg cap; demand ~100
__global__ void gnn_fused(const float* __restrict__ obs,
                          const float* __restrict__ be_b, const float* __restrict__ be_j,
                          const float* __restrict__ b_rel,
                          const float* __restrict__ W_dec, const float* __restrict__ b_dec,
                          const unsigned short* __restrict__ wsb,
                          float* __restrict__ out, int B)
{
    __shared__ __align__(16) unsigned short Xs[13*2048];   // 53248 B
    __shared__ __align__(16) unsigned short Yr[13*2048];   // 53248 B (also obs staging)

    const int tid  = threadIdx.x;
    const int wave = tid >> 6;     // 0..15
    const int half = wave >> 3;    // node-subset
    const int jt   = wave & 7;     // o-tile
    const int lane = tid & 63;
    const int q    = lane >> 4;    // quad 0..3
    const int c    = lane & 15;    // col-in-tile / graph-in-chunk
    const int g0   = blockIdx.x * GPB;
    const int o    = jt*16 + c;

    // per-thread LDS base for A-frag reads: frag(n,k) at xrd + n*2048 + k*512 shorts
    const unsigned short* xrd = Xs + q*128 + c*8;

    // in-edge adjacency of the fixed 24-edge tree (both directions folded in)
    static constexpr int INDEG[13]    = {4,2,2,1,2,2,1,2,2,1,2,2,1};
    static constexpr int INSRC[13][4] = {
        {1,4,7,10},{0,2,0,0},{1,3,0,0},{2,0,0,0},{0,5,0,0},{4,6,0,0},{5,0,0,0},
        {0,8,0,0},{7,9,0,0},{8,0,0,0},{0,11,0,0},{10,12,0,0},{11,0,0,0}};

    // ---------------- stage obs features into Yr ----------------
    // joints at Yr[jj*512 + fc*128 + g*8 + hi] (jj 0..11, f = fc*8+hi, f<9 valid)
    for (int s = tid; s < 6144; s += NT) {
        const int jj = s >> 9, rem = s & 511;
        const int fc = rem >> 7, g = (rem >> 3) & 15, hi = rem & 7;
        const int f = fc*8 + hi;
        float v = 0.0f;
        if (f < 9 && (g0 + g) < B)
            v = obs[(g0+g)*OBSROW + (f/3)*47 + 9 + (f%3)*12 + jj];
        Yr[s] = f2bf(v);
    }
    // base at Yr[6144 + fc*128 + g*8 + hi] (f = fc*8+hi, f<33 valid, K padded to 64)
    {
        const int s = tid;
        const int fc = s >> 7, rem = s & 127, g = rem >> 3, hi = rem & 7;
        const int f = fc*8 + hi;
        float v = 0.0f;
        if (f < 33 && (g0 + g) < B) {
            const int tt = f / 11, i2 = f % 11;   // BASE_IDX[i] = i<9 ? i : 36+i
            v = obs[(g0+g)*OBSROW + tt*47 + (i2 < 9 ? i2 : 36 + i2)];
        }
        Yr[6144 + s] = f2bf(v);
    }
    __syncthreads();

    // ---------------- encoders ----------------
    if (half == 0) {   // node 0 (base), K=64 -> 2 MFMAs
        const bf16x8 u0 = *(const bf16x8*)(wsb + WS_EB + o*64 + q*8);
        const bf16x8 u1 = *(const bf16x8*)(wsb + WS_EB + o*64 + 32 + q*8);
        const bf16x8 a0 = *(const bf16x8*)&Yr[6144 + q*128 + c*8];
        const bf16x8 a1 = *(const bf16x8*)&Yr[6144 + 512 + q*128 + c*8];
        f32x4 acc = {0.f,0.f,0.f,0.f};
        acc = __builtin_amdgcn_mfma_f32_16x16x32_bf16(a0, u0, acc, 0,0,0);
        acc = __builtin_amdgcn_mfma_f32_16x16x32_bf16(a1, u1, acc, 0,0,0);
        const float bias = be_b[o];
        #pragma unroll
        for (int r = 0; r < 4; r++)
            Xs[XIDX(0, jt*2 + (c>>3), q*4 + r, c & 7)] = f2bf(eluf(acc[r] + bias));
    }
    {   // joints: each wave does 6 of them for its o-tile, K=32 -> 1 MFMA each
        const bf16x8 uj = *(const bf16x8*)(wsb + WS_EJ + o*32 + q*8);
        const float bias = be_j[o];
        #pragma unroll
        for (int t2 = 0; t2 < 6; t2++) {
            const int jj = half*6 + t2;
            const bf16x8 a = *(const bf16x8*)&Yr[jj*512 + q*128 + c*8];
            f32x4 acc = {0.f,0.f,0.f,0.f};
            acc = __builtin_amdgcn_mfma_f32_16x16x32_bf16(a, uj, acc, 0,0,0);
            #pragma unroll
            for (int r = 0; r < 4; r++)
                Xs[XIDX(1+jj, jt*2 + (c>>3), q*4 + r, c & 7)] = f2bf(eluf(acc[r] + bias));
        }
    }
    __syncthreads();

    // ---------------- 3 GraphConv layers ----------------
    const int n0  = half*7;        // half0: nodes 0..6, half1: 7..12
    const int cnt = 7 - half;
    #pragma unroll 1
    for (int l = 0; l < 3; l++) {
        // this wave's B-frags (pre-converted bf16, direct 16B loads)
        bf16x8 brel[4], broot[4];
        #pragma unroll
        for (int k = 0; k < 4; k++) {
            brel[k]  = *(const bf16x8*)(wsb + l*16384 + o*128 + k*32 + q*8);
            broot[k] = *(const bf16x8*)(wsb + WS_ROOT + l*16384 + o*128 + k*32 + q*8);
        }
        // ---- phase 1: Yrel[n] -> LDS (bf16 C-layout), croot[n] -> regs.
        //      One A-read feeds both MFMA chains (2x reuse).
        f32x4 croot[7];
        #pragma unroll
        for (int idx = 0; idx < 7; idx++) {
            if (idx < cnt) {
                const int n = n0 + idx;
                f32x4 y = {0.f,0.f,0.f,0.f}, r = {0.f,0.f,0.f,0.f};
                #pragma unroll
                for (int k = 0; k < 4; k++) {
                    const bf16x8 xa = *(const bf16x8*)(xrd + n*2048 + k*512);
                    y = __builtin_amdgcn_mfma_f32_16x16x32_bf16(xa, brel[k],  y, 0,0,0);
                    r = __builtin_amdgcn_mfma_f32_16x16x32_bf16(xa, broot[k], r, 0,0,0);
                }
                croot[idx] = r;
                union { unsigned short s[4]; unsigned long long u; } p;
                p.s[0] = f2bf(y[0]); p.s[1] = f2bf(y[1]);
                p.s[2] = f2bf(y[2]); p.s[3] = f2bf(y[3]);
                *(unsigned long long*)&Yr[YIDX(n, jt, lane)] = p.u;
            }
        }
        __syncthreads();   // Yrel complete; all X reads done
        // ---- phase 2: acc = croot + sum_src Yrel[src]; elu; write X in place
        const float bias = b_rel[l*H + o];
        #pragma unroll
        for (int idx = 0; idx < 7; idx++) {
            if (idx < cnt) {
                const int n = n0 + idx;
                f32x4 acc = croot[idx];
                #pragma unroll
                for (int e = 0; e < 4; e++) {
                    if (e < INDEG[n]) {
                        const bf16x4 yv = *(const bf16x4*)&Yr[YIDX(INSRC[n][e], jt, lane)];
                        acc[0] += (float)yv[0]; acc[1] += (float)yv[1];
                        acc[2] += (float)yv[2]; acc[3] += (float)yv[3];
                    }
                }
                const int hc = jt*2 + (c >> 3);
                const int hi = c & 7;
                #pragma unroll
                for (int r = 0; r < 4; r++)
                    Xs[XIDX(n, hc, q*4 + r, hi)] = f2bf(eluf(acc[r] + bias));
            }
        }
        __syncthreads();   // new X visible (and Yr free for next layer)
    }

    // ---------------- decoder: out[g][j] = x[j+1]·W_dec + b_dec ----------------
    if (wave < 12) {
        // decoder base: hc = q*4 + hq  ->  h = q*32 + hq*8 + hi (matches wd indexing)
        const unsigned short* xdec = Xs + q*512 + c*8;
        float wd[32];
        #pragma unroll
        for (int i4 = 0; i4 < 8; i4++) {
            const float4 wv = *(const float4*)&W_dec[q*32 + i4*4];
            wd[i4*4+0] = wv.x; wd[i4*4+1] = wv.y; wd[i4*4+2] = wv.z; wd[i4*4+3] = wv.w;
        }
        const float bd = b_dec[0];
        const int j = wave;                 // joint 0..11
        float s = 0.0f;
        #pragma unroll
        for (int hq = 0; hq < 4; hq++) {    // lane covers h = q*32 + hq*8 + hi
            const bf16x8 xv = *(const bf16x8*)(xdec + (j+1)*2048 + hq*128);
            #pragma unroll
            for (int hi = 0; hi < 8; hi++)
                s += (float)xv[hi] * wd[hq*8 + hi];
        }
        s += __shfl_xor(s, 16);
        s += __shfl_xor(s, 32);
        if (q == 0 && (g0 + c) < B)
            out[(g0 + c)*12 + j] = s + bd;
    }
}

extern "C" void kernel_launch(void* const* d_in, const int* in_sizes, int n_in,
                              void* d_out, int out_size, void* d_ws, size_t ws_size,
                              hipStream_t stream) {
    const float* obs   = (const float*)d_in[0];
    const float* We_b  = (const float*)d_in[1];
    const float* be_b  = (const float*)d_in[2];
    const float* We_j  = (const float*)d_in[3];
    const float* be_j  = (const float*)d_in[4];
    const float* W_rel = (const float*)d_in[5];
    const float* W_root= (const float*)d_in[6];
    const float* b_rel = (const float*)d_in[7];
    const float* W_dec = (const float*)d_in[8];
    const float* b_dec = (const float*)d_in[9];
    // d_in[10]/d_in[11] (src/dst) are the fixed tree edges; adjacency is baked in.
    float* out = (float*)d_out;
    unsigned short* wsb = (unsigned short*)d_ws;   // 221 KB of bf16 weights

    const int B = in_sizes[0] / OBSROW;
    convert_weights<<<(WS_TOT + 255) / 256, 256, 0, stream>>>(W_rel, W_root, We_b, We_j, wsb);
    const int blocks = (B + GPB - 1) / GPB;
    gnn_fused<<<blocks, NT, 0, stream>>>(obs, be_b, be_j, b_rel, W_dec, b_dec,
                                         wsb, out, B);
}